// Round 5
// baseline (467.987 us; speedup 1.0000x reference)
//
#include <hip/hip_runtime.h>
#include <hip/hip_bf16.h>

typedef unsigned short ushort_t;
typedef __attribute__((ext_vector_type(8))) short short8v;
typedef __attribute__((ext_vector_type(4))) float float4v;

#define NP   4
#define NB   128
#define NIMG 512   // NP*NB
#define CIN  32
#define KOUT 64

// fp32 -> bf16 round-to-nearest-even
__device__ __forceinline__ ushort_t f2bf(float f) {
    unsigned u = __float_as_uint(f);
    unsigned r = u + 0x7fffu + ((u >> 16) & 1u);
    return (ushort_t)(r >> 16);
}

// ---------------------------------------------------------------------------
// Kernel 1: w_t[rs][outk][c] (bf16) from fp32 conv_w[outk][c][r][s], rs=r*3+s.
// B^T (n-major, k-inner) layout for the MFMA B-fragment.
// ---------------------------------------------------------------------------
__global__ void prep_kernel(const float* __restrict__ conv_w,
                            ushort_t* __restrict__ w_t) {
    int i = blockIdx.x * 256 + threadIdx.x;
    if (i < 9 * KOUT * CIN) {
        int rs  = i >> 11;
        int rem = i & 2047;
        int ko  = rem >> 5;
        int c   = rem & 31;
        w_t[i] = f2bf(conv_w[ko * 288 + c * 9 + rs]);
    }
}

// ---------------------------------------------------------------------------
// Kernel 2 v5: PERSISTENT per-image block with 18-row LDS ring buffer.
// One block per image (512 blocks, 2/CU, all resident). 8 strips of 8 output
// rows processed sequentially; each input row read from HBM exactly once
// (66 row-reads/image incl. circular wrap vs 80 for separate strip blocks):
// x traffic 335.5 -> 276.8 MB.
//
// Ring: slot(gr) = (gr+1) mod 18 for global input row gr in -1..64.
// Strip k computes from slots (8k..8k+9)%18; while computing, rows for strip
// k+1 are staged into slots (8k+10..8k+17)%18 — disjoint mod 18 from the
// compute window, so ONE __syncthreads per strip is sufficient (staging for
// strip k+2 would collide with compute window k; the end-of-strip barrier
// fences that).
//
// R2 spill lesson applied: the strip loop is `#pragma unroll 1` so the
// scheduler can NEVER have two 128-reg accumulator sets live (the R2
// catastrophe). sums[] are per-strip and stored to global per strip; nothing
// fat is live across strip iterations. Register budget == R1 structure:
// 128 AGPR acc + <=128 VGPR. DO NOT unroll the strip loop.
//
// Halo columns eliminated: LDS is [18][64][32] and the A-read column wraps
// mod 64 in the address math (halos were circular copies anyway).
// Channel XOR swizzle unchanged: logical ch c at (row,col) lives at physical
// c ^ (((col>>3)&3)<<3); 8-channel A-fragments stay contiguous (ds_read_b128).
// ---------------------------------------------------------------------------
__global__ __launch_bounds__(256, 2)
void conv_pool_kernel(const float* __restrict__ x,
                      const float* __restrict__ conv_b,
                      const ushort_t* __restrict__ w_t,
                      float* __restrict__ partials) {
    __shared__ ushort_t xs[18 * 64 * 32];   // 73,728 B ring

    const int tid = threadIdx.x;
    const int n   = blockIdx.x;             // image 0..511
    const long xbase = (long)n * (CIN * 64 * 64);

    const int wq  = tid & 15;               // 4-col chunk 0..15
    const int cg  = (tid >> 4) & 7;         // 4-ch group 0..7
    const int lr0 = tid >> 7;               // 0 or 1

    // ---- prologue: stage input rows -1..8 into slots 0..9 ----
    {
        union F4 { float4 v; float f[4]; };
        F4 L[5][4];
        #pragma unroll
        for (int t = 0; t < 5; ++t) {
            const int lr = lr0 + 2 * t;          // slot 0..9
            const int gh = (lr + 63) & 63;       // global row lr-1
            #pragma unroll
            for (int cc = 0; cc < 4; ++cc)
                L[t][cc].v = *(const float4*)(x + xbase +
                            ((cg * 4 + cc) * 4096 + gh * 64 + wq * 4));
        }
        #pragma unroll
        for (int t = 0; t < 5; ++t) {
            const int slot = lr0 + 2 * t;
            #pragma unroll
            for (int j = 0; j < 4; ++j) {
                const int col  = wq * 4 + j;
                const int cpos = (cg * 4) ^ (((col >> 3) & 3) << 3);
                union { uint2 v; ushort_t s[4]; } tv;
                tv.s[0] = f2bf(L[t][0].f[j]); tv.s[1] = f2bf(L[t][1].f[j]);
                tv.s[2] = f2bf(L[t][2].f[j]); tv.s[3] = f2bf(L[t][3].f[j]);
                *(uint2*)&xs[(slot * 64 + col) * 32 + cpos] = tv.v;
            }
        }
    }

    const int lane = tid & 63;
    const int wv   = tid >> 6;
    const int m16  = lane & 15;
    const int q    = lane >> 4;

    // strip-independent column part of A-read addresses:
    // pixel col = (mt&3)*16 + m16 + s - 1 (mod 64, circular)
    int cpart[8][3];
    #pragma unroll
    for (int mt = 0; mt < 8; ++mt) {
        const int lc = (mt & 3) * 16 + m16;
        #pragma unroll
        for (int s = 0; s < 3; ++s) {
            const int col = (lc + s + 63) & 63;
            const int cr  = (q ^ ((col >> 3) & 3)) << 3;
            cpart[mt][s] = col * 32 + cr;
        }
    }

    const ushort_t* wt_lane = w_t + (m16 * 32 + (q << 3));

    float bias[4];
    #pragma unroll
    for (int nt = 0; nt < 4; ++nt) bias[nt] = conv_b[nt * 16 + m16];

    __syncthreads();   // prologue staging visible to all waves

    int sbase = 0;     // (8k) mod 18
    #pragma unroll 1
    for (int k = 0; k < 8; ++k) {
        // ---- stage rows 8k+9..8k+16 for strip k+1 (slots sbase+10+rr mod 18)
        if (k < 7) {
            union F4 { float4 v; float f[4]; };
            F4 L[4][4];
            #pragma unroll
            for (int t = 0; t < 4; ++t) {
                const int rr = lr0 + 2 * t;
                const int gh = (8 * k + 9 + rr) & 63;
                #pragma unroll
                for (int cc = 0; cc < 4; ++cc)
                    L[t][cc].v = *(const float4*)(x + xbase +
                                ((cg * 4 + cc) * 4096 + gh * 64 + wq * 4));
            }
            #pragma unroll
            for (int t = 0; t < 4; ++t) {
                const int rr = lr0 + 2 * t;
                int slot = sbase + 10 + rr; if (slot >= 18) slot -= 18;
                #pragma unroll
                for (int j = 0; j < 4; ++j) {
                    const int col  = wq * 4 + j;
                    const int cpos = (cg * 4) ^ (((col >> 3) & 3) << 3);
                    union { uint2 v; ushort_t s[4]; } tv;
                    tv.s[0] = f2bf(L[t][0].f[j]); tv.s[1] = f2bf(L[t][1].f[j]);
                    tv.s[2] = f2bf(L[t][2].f[j]); tv.s[3] = f2bf(L[t][3].f[j]);
                    *(uint2*)&xs[(slot * 64 + col) * 32 + cpos] = tv.v;
                }
            }
        }

        // ---- row bases for this strip: input row = 8k + lpr + r - 1,
        // slot = (sbase + wv*2 + j2) mod 18 with j2 = (mt>>2)+r in 0..3
        int rowbase[4];
        #pragma unroll
        for (int j2 = 0; j2 < 4; ++j2) {
            int slot = sbase + wv * 2 + j2; if (slot >= 18) slot -= 18;
            rowbase[j2] = slot * (64 * 32);
        }

        // ---- MFMA: 9 taps x K=32 channels ----
        float4v accv[8][4];
        #pragma unroll
        for (int mt = 0; mt < 8; ++mt)
            #pragma unroll
            for (int nt = 0; nt < 4; ++nt)
                accv[mt][nt] = (float4v){0.f, 0.f, 0.f, 0.f};

        #pragma unroll
        for (int r = 0; r < 3; ++r) {
            #pragma unroll
            for (int s = 0; s < 3; ++s) {
                const int rs = r * 3 + s;
                short8v bfr[4];
                #pragma unroll
                for (int nt = 0; nt < 4; ++nt)
                    bfr[nt] = *(const short8v*)(wt_lane + (rs * 64 + nt * 16) * 32);
                #pragma unroll
                for (int mt = 0; mt < 8; ++mt) {
                    short8v afr = *(const short8v*)
                        &xs[rowbase[(mt >> 2) + r] + cpart[mt][s]];
                    #pragma unroll
                    for (int nt = 0; nt < 4; ++nt)
                        accv[mt][nt] = __builtin_amdgcn_mfma_f32_16x16x32_bf16(
                            afr, bfr[nt], accv[mt][nt], 0, 0, 0);
                }
            }
        }

        // ---- fold strip into pool partial: bias + ReLU, reduce, store ----
        float sums[4] = {0.f, 0.f, 0.f, 0.f};
        #pragma unroll
        for (int nt = 0; nt < 4; ++nt)
            #pragma unroll
            for (int mt = 0; mt < 8; ++mt)
                #pragma unroll
                for (int rg = 0; rg < 4; ++rg)
                    sums[nt] += fmaxf(accv[mt][nt][rg] + bias[nt], 0.f);

        #pragma unroll
        for (int nt = 0; nt < 4; ++nt) {
            float sv = sums[nt];
            sv += __shfl_xor(sv, 16);
            sv += __shfl_xor(sv, 32);
            if (lane < 16)
                partials[(long)(((n * 8 + k) * 4 + wv)) * 64 + nt * 16 + lane] = sv;
        }

        __syncthreads();   // strip k compute done before staging strip k+2
        sbase += 8; if (sbase >= 18) sbase -= 18;
    }
}

// ---------------------------------------------------------------------------
// Kernel 3: graph MLP, one block per (batch b, recv node j) -> 512 blocks
// (2 blocks/CU). Each phase is exactly 1 element/thread.
// nodes[p][h] = sum over 32 sub-partials (8 strips x 4 waves) / 4096.
// ---------------------------------------------------------------------------
__global__ __launch_bounds__(256)
void mlp_kernel(const float* __restrict__ partials,
                const float* __restrict__ e_w1, const float* __restrict__ e_b1,
                const float* __restrict__ e_w2, const float* __restrict__ e_b2,
                const float* __restrict__ o_w1, const float* __restrict__ o_b1,
                const float* __restrict__ o_w2, const float* __restrict__ o_b2,
                float* __restrict__ out) {
    __shared__ float nodes_s[256], h1s[256], e2s[256], msgs[64];

    const int tid = threadIdx.x;
    const int b   = blockIdx.x >> 2;   // batch 0..127
    const int j   = blockIdx.x & 3;    // recv node 0..3
    const int i   = tid >> 6;          // send node 0..3 (one per wave)
    const int h   = tid & 63;          // hidden lane

    // nodes for all 4 senders (recv j is one of them)
    {
        const float* pp = partials + (long)(i * 128 + b) * 32 * 64 + h;
        float s = 0.f;
        #pragma unroll
        for (int hb = 0; hb < 32; ++hb) s += pp[hb * 64];
        nodes_s[tid] = s * (1.f / 4096.f);
    }
    __syncthreads();

    // h1 for the 4 edges (i, j): [node_i(send) | node_j(recv)] @ e_w1
    {
        float sum = e_b1[h];
        const float* ni = &nodes_s[i * 64];
        const float* nj = &nodes_s[j * 64];
        #pragma unroll
        for (int k = 0; k < 64; ++k)
            sum += ni[k] * e_w1[k * 64 + h] + nj[k] * e_w1[(64 + k) * 64 + h];
        h1s[tid] = fmaxf(sum, 0.f);
    }
    __syncthreads();

    // e2 = relu(h1 @ e_w2 + e_b2)
    {
        float sum = e_b2[h];
        const float* he = &h1s[i * 64];
        #pragma unroll
        for (int k = 0; k < 64; ++k)
            sum += he[k] * e_w2[k * 64 + h];
        e2s[tid] = fmaxf(sum, 0.f);
    }
    __syncthreads();

    // msg[j] = mean over send axis i
    if (tid < 64)
        msgs[tid] = 0.25f * (e2s[tid] + e2s[64 + tid] +
                             e2s[128 + tid] + e2s[192 + tid]);
    __syncthreads();

    // o1 = relu(msg @ o_w1 + o_b1); out[b][j] = o1 . o_w2 + o_b2 (wave 0)
    if (tid < 64) {
        float sum = o_b1[tid];
        #pragma unroll
        for (int k = 0; k < 64; ++k)
            sum += msgs[k] * o_w1[k * 64 + tid];
        float v = fmaxf(sum, 0.f) * o_w2[tid];
        v += __shfl_xor(v, 1);
        v += __shfl_xor(v, 2);
        v += __shfl_xor(v, 4);
        v += __shfl_xor(v, 8);
        v += __shfl_xor(v, 16);
        v += __shfl_xor(v, 32);
        if (tid == 0) out[b * 4 + j] = v + o_b2[0];
    }
}

// ---------------------------------------------------------------------------
extern "C" void kernel_launch(void* const* d_in, const int* in_sizes, int n_in,
                              void* d_out, int out_size, void* d_ws, size_t ws_size,
                              hipStream_t stream) {
    const float* x      = (const float*)d_in[0];
    const float* conv_w = (const float*)d_in[1];
    const float* conv_b = (const float*)d_in[2];
    const float* e_w1   = (const float*)d_in[3];
    const float* e_b1   = (const float*)d_in[4];
    const float* e_w2   = (const float*)d_in[5];
    const float* e_b2   = (const float*)d_in[6];
    const float* o_w1   = (const float*)d_in[7];
    const float* o_b1   = (const float*)d_in[8];
    const float* o_w2   = (const float*)d_in[9];
    const float* o_b2   = (const float*)d_in[10];

    // ws: [0, 2MB) fp32 pool partials [512 img][8 strip][4 wave][64 ch]
    //     (0.5 MB used); then w_t bf16 (36 KB) at +2 MB.
    float*    partials = (float*)d_ws;
    ushort_t* w_t = (ushort_t*)((char*)d_ws + (size_t)2 * 1024 * 1024);

    prep_kernel<<<72, 256, 0, stream>>>(conv_w, w_t);
    conv_pool_kernel<<<NIMG, 256, 0, stream>>>(x, conv_b, w_t, partials);
    mlp_kernel<<<NB * NP, 256, 0, stream>>>(partials, e_w1, e_b1, e_w2, e_b2,
                                            o_w1, o_b1, o_w2, o_b2,
                                            (float*)d_out);
}